// Round 1
// baseline (199.639 us; speedup 1.0000x reference)
//
#include <hip/hip_runtime.h>

// ---- types ----
typedef __bf16 bf16x8 __attribute__((ext_vector_type(8)));
typedef float  f32x4  __attribute__((ext_vector_type(4)));

__device__ __forceinline__ short f2bf(float f) {
  union { float f; unsigned u; } v; v.f = f;
  unsigned r = v.u + 0x7fffu + ((v.u >> 16) & 1u);
  return (short)(r >> 16);
}

// ---- cast x fp32 -> bf16 (vectorized) ----
__global__ __launch_bounds__(256) void cast_x_kernel(const float* __restrict__ in,
                                                     short* __restrict__ out, int n4) {
  int i = blockIdx.x * 256 + threadIdx.x;
  if (i >= n4) return;
  float4 f = reinterpret_cast<const float4*>(in)[i];
  short4 o;
  o.x = f2bf(f.x); o.y = f2bf(f.y); o.z = f2bf(f.z); o.w = f2bf(f.w);
  reinterpret_cast<short4*>(out)[i] = o;
}

// ---- transpose + cast: in[R][Cc] fp32 -> out[Cc][R] bf16 ----
__global__ __launch_bounds__(256) void transpose_cast(const float* __restrict__ in,
                                                      short* __restrict__ out, int R, int Cc) {
  __shared__ short tile[64][65];
  int bx = blockIdx.x * 64;  // col in input
  int by = blockIdx.y * 64;  // row in input
  int tx = threadIdx.x & 63, ty = threadIdx.x >> 6;
  #pragma unroll
  for (int i = ty; i < 64; i += 4)
    tile[i][tx] = f2bf(in[(size_t)(by + i) * Cc + bx + tx]);
  __syncthreads();
  #pragma unroll
  for (int i = ty; i < 64; i += 4)
    out[(size_t)(bx + i) * R + by + tx] = tile[tx][i];
}

// ---- GEMM1: qkv = x_bf[4096][1024] * Wqkv_t[3072][1024]^T + bqkv
//      scatter into q/k/v [B=2][H=16][T=2048][D=64] bf16, q scaled by 0.125 ----
__global__ __launch_bounds__(256) void gemm_qkv(const short* __restrict__ A,
                                                const short* __restrict__ Bt,
                                                const float* __restrict__ bias,
                                                short* __restrict__ qo,
                                                short* __restrict__ ko,
                                                short* __restrict__ vo) {
  const int K = 1024;
  __shared__ short Al[128][72];
  __shared__ short Bl[128][72];
  int tid = threadIdx.x;
  int mtile = blockIdx.y * 128, ntile = blockIdx.x * 128;
  int w = tid >> 6, l = tid & 63;
  int wr = w >> 1, wc = w & 1;
  int lr = l & 15, lg = l >> 4;

  f32x4 zero4 = {0.f, 0.f, 0.f, 0.f};
  f32x4 acc[4][4];
  #pragma unroll
  for (int i = 0; i < 4; ++i)
    #pragma unroll
    for (int j = 0; j < 4; ++j) acc[i][j] = zero4;

  for (int k0 = 0; k0 < K; k0 += 64) {
    __syncthreads();
    #pragma unroll
    for (int c = 0; c < 4; ++c) {
      int idx = tid + c * 256;
      int row = idx >> 3, kc = idx & 7;
      *reinterpret_cast<uint4*>(&Al[row][kc * 8]) =
          *reinterpret_cast<const uint4*>(&A[(size_t)(mtile + row) * K + k0 + kc * 8]);
      *reinterpret_cast<uint4*>(&Bl[row][kc * 8]) =
          *reinterpret_cast<const uint4*>(&Bt[(size_t)(ntile + row) * K + k0 + kc * 8]);
    }
    __syncthreads();
    #pragma unroll
    for (int kk = 0; kk < 2; ++kk) {
      bf16x8 af[4], bfr[4];
      #pragma unroll
      for (int i = 0; i < 4; ++i)
        af[i] = *reinterpret_cast<const bf16x8*>(&Al[wr * 64 + i * 16 + lr][kk * 32 + lg * 8]);
      #pragma unroll
      for (int j = 0; j < 4; ++j)
        bfr[j] = *reinterpret_cast<const bf16x8*>(&Bl[wc * 64 + j * 16 + lr][kk * 32 + lg * 8]);
      #pragma unroll
      for (int i = 0; i < 4; ++i)
        #pragma unroll
        for (int j = 0; j < 4; ++j)
          acc[i][j] = __builtin_amdgcn_mfma_f32_16x16x32_bf16(af[i], bfr[j], acc[i][j], 0, 0, 0);
    }
  }

  #pragma unroll
  for (int j = 0; j < 4; ++j) {
    int n = ntile + wc * 64 + j * 16 + lr;   // 0..3071
    float bv = bias[n];
    int sec = n >> 10;          // 0=q 1=k 2=v (uniform per block: ntile 128-aligned)
    int ch = n & 1023;
    int h = ch >> 6, d = ch & 63;
    short* dst = (sec == 0) ? qo : ((sec == 1) ? ko : vo);
    float sc = (sec == 0) ? 0.125f : 1.0f;
    #pragma unroll
    for (int i = 0; i < 4; ++i) {
      #pragma unroll
      for (int r = 0; r < 4; ++r) {
        int m = mtile + wr * 64 + i * 16 + lg * 4 + r;  // token index 0..4095
        int bb = m >> 11, t = m & 2047;
        dst[(size_t)((bb * 16 + h) * 2048 + t) * 64 + d] = f2bf((acc[i][j][r] + bv) * sc);
      }
    }
  }
}

// ---- flash attention: q,k,v [BH=32][T=2048][D=64] bf16 -> y [B][T][C] bf16 ----
__global__ __launch_bounds__(256) void attn_kernel(const short* __restrict__ q,
                                                   const short* __restrict__ k,
                                                   const short* __restrict__ v,
                                                   short* __restrict__ y) {
  __shared__ short Klds[64][72];      // [kv][d]
  __shared__ short Vt[64][72];        // [d][kv]
  __shared__ short Plds[4][16][72];   // per-wave [qrow][kv]
  int tid = threadIdx.x;
  int w = tid >> 6, l = tid & 63;
  int lr = l & 15, lg = l >> 4;
  int bh = blockIdx.y;                // b*16+h
  int q0 = blockIdx.x * 64;
  const short* qb = q + (size_t)bh * 2048 * 64;
  const short* kb = k + (size_t)bh * 2048 * 64;
  const short* vb = v + (size_t)bh * 2048 * 64;

  // Q fragments (16 rows per wave), q already scaled by 1/sqrt(D)
  bf16x8 qa[2];
  int qrow = q0 + w * 16 + lr;
  #pragma unroll
  for (int kk = 0; kk < 2; ++kk)
    qa[kk] = *reinterpret_cast<const bf16x8*>(&qb[(size_t)qrow * 64 + kk * 32 + lg * 8]);

  float m_i[4], l_i[4];
  f32x4 zero4 = {0.f, 0.f, 0.f, 0.f};
  f32x4 yacc[4];
  #pragma unroll
  for (int r = 0; r < 4; ++r) { m_i[r] = -1e30f; l_i[r] = 0.f; }
  #pragma unroll
  for (int gd = 0; gd < 4; ++gd) yacc[gd] = zero4;

  int ntiles = q0 / 64 + 1;
  for (int it = 0; it < ntiles; ++it) {
    int kv0 = it * 64;
    __syncthreads();   // previous tile fully consumed
    // stage K tile [64][64] row-major (coalesced 16B)
    #pragma unroll
    for (int c = 0; c < 2; ++c) {
      int idx = tid + c * 256;
      int row = idx >> 3, kc = idx & 7;
      *reinterpret_cast<uint4*>(&Klds[row][kc * 8]) =
          *reinterpret_cast<const uint4*>(&kb[(size_t)(kv0 + row) * 64 + kc * 8]);
    }
    // stage V transposed: Vt[d][kv]  (scalar loads coalesced across lanes)
    {
      int d_ = tid & 63, kc0 = tid >> 6;
      #pragma unroll
      for (int c = 0; c < 2; ++c) {
        int kc = kc0 + c * 4;
        unsigned a0 = (unsigned short)vb[(size_t)(kv0 + kc * 8 + 0) * 64 + d_];
        unsigned a1 = (unsigned short)vb[(size_t)(kv0 + kc * 8 + 1) * 64 + d_];
        unsigned a2 = (unsigned short)vb[(size_t)(kv0 + kc * 8 + 2) * 64 + d_];
        unsigned a3 = (unsigned short)vb[(size_t)(kv0 + kc * 8 + 3) * 64 + d_];
        unsigned a4 = (unsigned short)vb[(size_t)(kv0 + kc * 8 + 4) * 64 + d_];
        unsigned a5 = (unsigned short)vb[(size_t)(kv0 + kc * 8 + 5) * 64 + d_];
        unsigned a6 = (unsigned short)vb[(size_t)(kv0 + kc * 8 + 6) * 64 + d_];
        unsigned a7 = (unsigned short)vb[(size_t)(kv0 + kc * 8 + 7) * 64 + d_];
        uint4 pk;
        pk.x = a0 | (a1 << 16); pk.y = a2 | (a3 << 16);
        pk.z = a4 | (a5 << 16); pk.w = a6 | (a7 << 16);
        *reinterpret_cast<uint4*>(&Vt[d_][kc * 8]) = pk;
      }
    }
    __syncthreads();

    // S = Q K^T  (16 q-rows x 64 kv per wave)
    f32x4 s[4];
    #pragma unroll
    for (int g = 0; g < 4; ++g) s[g] = zero4;
    #pragma unroll
    for (int g = 0; g < 4; ++g)
      #pragma unroll
      for (int kk = 0; kk < 2; ++kk) {
        bf16x8 kf = *reinterpret_cast<const bf16x8*>(&Klds[g * 16 + lr][kk * 32 + lg * 8]);
        s[g] = __builtin_amdgcn_mfma_f32_16x16x32_bf16(qa[kk], kf, s[g], 0, 0, 0);
      }

    // causal mask (only diagonal tile needs it; kv0 steps 64-aligned == q0)
    if (kv0 == q0) {
      #pragma unroll
      for (int g = 0; g < 4; ++g)
        #pragma unroll
        for (int r = 0; r < 4; ++r) {
          int col = kv0 + g * 16 + lr;
          int row = q0 + w * 16 + lg * 4 + r;
          if (col > row) s[g][r] = -1e30f;
        }
    }

    // online softmax (row stats across 16-lane groups)
    #pragma unroll
    for (int r = 0; r < 4; ++r) {
      float tm = fmaxf(fmaxf(s[0][r], s[1][r]), fmaxf(s[2][r], s[3][r]));
      tm = fmaxf(tm, __shfl_xor(tm, 1));
      tm = fmaxf(tm, __shfl_xor(tm, 2));
      tm = fmaxf(tm, __shfl_xor(tm, 4));
      tm = fmaxf(tm, __shfl_xor(tm, 8));
      float mnew = fmaxf(m_i[r], tm);
      float scl = __expf(m_i[r] - mnew);
      m_i[r] = mnew;
      float rsum = 0.f;
      #pragma unroll
      for (int g = 0; g < 4; ++g) {
        float p = __expf(s[g][r] - mnew);
        s[g][r] = p;
        rsum += p;
      }
      rsum += __shfl_xor(rsum, 1);
      rsum += __shfl_xor(rsum, 2);
      rsum += __shfl_xor(rsum, 4);
      rsum += __shfl_xor(rsum, 8);
      l_i[r] = l_i[r] * scl + rsum;
      #pragma unroll
      for (int gd = 0; gd < 4; ++gd) yacc[gd][r] *= scl;
    }

    // P -> per-wave LDS (re-fragment for PV A operand); same-wave RAW is in-order
    #pragma unroll
    for (int g = 0; g < 4; ++g)
      #pragma unroll
      for (int r = 0; r < 4; ++r)
        Plds[w][lg * 4 + r][g * 16 + lr] = f2bf(s[g][r]);

    bf16x8 pa[2];
    #pragma unroll
    for (int kk = 0; kk < 2; ++kk)
      pa[kk] = *reinterpret_cast<const bf16x8*>(&Plds[w][lr][kk * 32 + lg * 8]);
    #pragma unroll
    for (int gd = 0; gd < 4; ++gd) {
      #pragma unroll
      for (int kk = 0; kk < 2; ++kk) {
        bf16x8 vf = *reinterpret_cast<const bf16x8*>(&Vt[gd * 16 + lr][kk * 32 + lg * 8]);
        yacc[gd] = __builtin_amdgcn_mfma_f32_16x16x32_bf16(pa[kk], vf, yacc[gd], 0, 0, 0);
      }
    }
  }

  // write y [B][T][H*D] bf16
  int b_ = bh >> 4, h_ = bh & 15;
  float inv[4];
  #pragma unroll
  for (int r = 0; r < 4; ++r) inv[r] = 1.0f / l_i[r];
  #pragma unroll
  for (int gd = 0; gd < 4; ++gd)
    #pragma unroll
    for (int r = 0; r < 4; ++r) {
      int row = q0 + w * 16 + lg * 4 + r;
      y[(size_t)(b_ * 2048 + row) * 1024 + h_ * 64 + gd * 16 + lr] =
          f2bf(yacc[gd][r] * inv[r]);
    }
}

// ---- GEMM3: out fp32 = y_bf[4096][1024] * Wproj_t[1024][1024]^T + bproj ----
__global__ __launch_bounds__(256) void gemm_proj(const short* __restrict__ A,
                                                 const short* __restrict__ Bt,
                                                 const float* __restrict__ bias,
                                                 float* __restrict__ out) {
  const int K = 1024;
  __shared__ short Al[128][72];
  __shared__ short Bl[128][72];
  int tid = threadIdx.x;
  int mtile = blockIdx.y * 128, ntile = blockIdx.x * 128;
  int w = tid >> 6, l = tid & 63;
  int wr = w >> 1, wc = w & 1;
  int lr = l & 15, lg = l >> 4;

  f32x4 zero4 = {0.f, 0.f, 0.f, 0.f};
  f32x4 acc[4][4];
  #pragma unroll
  for (int i = 0; i < 4; ++i)
    #pragma unroll
    for (int j = 0; j < 4; ++j) acc[i][j] = zero4;

  for (int k0 = 0; k0 < K; k0 += 64) {
    __syncthreads();
    #pragma unroll
    for (int c = 0; c < 4; ++c) {
      int idx = tid + c * 256;
      int row = idx >> 3, kc = idx & 7;
      *reinterpret_cast<uint4*>(&Al[row][kc * 8]) =
          *reinterpret_cast<const uint4*>(&A[(size_t)(mtile + row) * K + k0 + kc * 8]);
      *reinterpret_cast<uint4*>(&Bl[row][kc * 8]) =
          *reinterpret_cast<const uint4*>(&Bt[(size_t)(ntile + row) * K + k0 + kc * 8]);
    }
    __syncthreads();
    #pragma unroll
    for (int kk = 0; kk < 2; ++kk) {
      bf16x8 af[4], bfr[4];
      #pragma unroll
      for (int i = 0; i < 4; ++i)
        af[i] = *reinterpret_cast<const bf16x8*>(&Al[wr * 64 + i * 16 + lr][kk * 32 + lg * 8]);
      #pragma unroll
      for (int j = 0; j < 4; ++j)
        bfr[j] = *reinterpret_cast<const bf16x8*>(&Bl[wc * 64 + j * 16 + lr][kk * 32 + lg * 8]);
      #pragma unroll
      for (int i = 0; i < 4; ++i)
        #pragma unroll
        for (int j = 0; j < 4; ++j)
          acc[i][j] = __builtin_amdgcn_mfma_f32_16x16x32_bf16(af[i], bfr[j], acc[i][j], 0, 0, 0);
    }
  }

  #pragma unroll
  for (int j = 0; j < 4; ++j) {
    int n = ntile + wc * 64 + j * 16 + lr;
    float bv = bias[n];
    #pragma unroll
    for (int i = 0; i < 4; ++i) {
      #pragma unroll
      for (int r = 0; r < 4; ++r) {
        int m = mtile + wr * 64 + i * 16 + lg * 4 + r;
        out[(size_t)m * 1024 + n] = acc[i][j][r] + bv;
      }
    }
  }
}

extern "C" void kernel_launch(void* const* d_in, const int* in_sizes, int n_in,
                              void* d_out, int out_size, void* d_ws, size_t ws_size,
                              hipStream_t stream) {
  const float* x     = (const float*)d_in[0];   // [2][2048][1024]
  const float* Wqkv  = (const float*)d_in[1];   // [1024][3072]
  const float* bqkv  = (const float*)d_in[2];   // [3072]
  const float* Wproj = (const float*)d_in[3];   // [1024][1024]
  const float* bproj = (const float*)d_in[4];   // [1024]
  float* out = (float*)d_out;                   // [2][2048][1024] fp32

  const size_t M4 = 4096ull * 1024ull;  // 4M elements
  short* ws = (short*)d_ws;
  short* x_bf    = ws;                 // 4M shorts; later reused as y
  short* wqkv_t  = ws + M4;            // 3M
  short* wproj_t = ws + M4 + 3ull * 1024 * 1024;       // 1M
  short* qb      = wproj_t + 1024ull * 1024;           // 4M
  short* kb      = qb + M4;                            // 4M
  short* vb      = kb + M4;                            // 4M
  short* yb      = x_bf;   // alias: x_bf dead after gemm_qkv

  cast_x_kernel<<<4096, 256, 0, stream>>>(x, x_bf, (int)(M4 / 4));
  transpose_cast<<<dim3(48, 16), 256, 0, stream>>>(Wqkv, wqkv_t, 1024, 3072);
  transpose_cast<<<dim3(16, 16), 256, 0, stream>>>(Wproj, wproj_t, 1024, 1024);
  gemm_qkv<<<dim3(24, 32), 256, 0, stream>>>(x_bf, wqkv_t, bqkv, qb, kb, vb);
  attn_kernel<<<dim3(32, 32), 256, 0, stream>>>(qb, kb, vb, yb);
  gemm_proj<<<dim3(8, 32), 256, 0, stream>>>(yb, wproj_t, bproj, out);
}